// Round 1
// baseline (299.183 us; speedup 1.0000x reference)
//
#include <hip/hip_runtime.h>
#include <cstdint>
#include <cstddef>

#define NN 8192
#define NF 512

typedef __attribute__((ext_vector_type(8))) short bf16x8;
typedef __attribute__((ext_vector_type(4))) float f32x4;

__device__ __forceinline__ unsigned short f2bf_bits(float f) {
  unsigned u = __builtin_bit_cast(unsigned, f);
  u += 0x7FFFu + ((u >> 16) & 1u);   // round-to-nearest-even
  return (unsigned short)(u >> 16);
}

__device__ __forceinline__ bf16x8 cvt8(float4 a, float4 b) {
  bf16x8 r;
  r[0] = (short)f2bf_bits(a.x); r[1] = (short)f2bf_bits(a.y);
  r[2] = (short)f2bf_bits(a.z); r[3] = (short)f2bf_bits(a.w);
  r[4] = (short)f2bf_bits(b.x); r[5] = (short)f2bf_bits(b.y);
  r[6] = (short)f2bf_bits(b.z); r[7] = (short)f2bf_bits(b.w);
  return r;
}

__device__ __forceinline__ void gld_lds16(const void* g, void* l) {
  __builtin_amdgcn_global_load_lds(
      (const __attribute__((address_space(1))) unsigned int*)g,
      (__attribute__((address_space(3))) unsigned int*)l, 16, 0, 0);
}

// K1: deg[i] = sum_j adj[i][j] + 1 (self loop); dinv[i] = rsqrt(deg)
__global__ void k_rowsum(const float* __restrict__ adj, float* __restrict__ dinv) {
  const int row = blockIdx.x;
  const float4* p = (const float4*)(adj + (size_t)row * NN);
  float s = 0.f;
#pragma unroll
  for (int j = 0; j < 8; ++j) {
    float4 v = p[j * 256 + threadIdx.x];
    s += (v.x + v.y) + (v.z + v.w);
  }
#pragma unroll
  for (int off = 32; off > 0; off >>= 1) s += __shfl_down(s, off, 64);
  __shared__ float red[4];
  if ((threadIdx.x & 63) == 0) red[threadIdx.x >> 6] = s;
  __syncthreads();
  if (threadIdx.x == 0) {
    float deg = red[0] + red[1] + red[2] + red[3] + 1.0f;
    dinv[row] = (deg > 0.f) ? (1.0f / sqrtf(deg)) : 0.f;
  }
}

// K2: transpose fp32 [rows][cols] -> bf16 [cols][rows]; optional row-scale by dinv[row]
template <bool SCALE>
__global__ void k_transpose(const float* __restrict__ src, int rows, int cols,
                            const float* __restrict__ dinv, short* __restrict__ dst) {
  __shared__ float tile[32][33];
  const int c0 = blockIdx.x * 32, r0 = blockIdx.y * 32;
  const int tx = threadIdx.x & 31, ty = threadIdx.x >> 5;
#pragma unroll
  for (int i = 0; i < 32; i += 8) {
    float v = src[(size_t)(r0 + ty + i) * cols + c0 + tx];
    if (SCALE) v *= dinv[r0 + ty + i];
    tile[ty + i][tx] = v;
  }
  __syncthreads();
#pragma unroll
  for (int i = 0; i < 32; i += 8)
    dst[(size_t)(c0 + ty + i) * rows + r0 + tx] = (short)f2bf_bits(tile[tx][ty + i]);
}

// GEMM: C[M][N] = A[M][K] * Bt[N][K]^T, 128x128 tile, BK=64, 4 waves (2x2),
// 16x16x32 bf16 MFMA, XOR-swizzled LDS (chunk c of row r holds logical chunk c^(r&7)).
// A_F32: A is fp32 in global, reg-staged + converted.  Else A bf16 via global_load_lds.
// GCN_EPI: h = d_i*acc + d_i^2*feat[i][n], write bf16.  Else write fp32.
template <bool A_F32, bool GCN_EPI>
__global__ __launch_bounds__(256, 2)
void k_gemm(const void* __restrict__ Ap, const short* __restrict__ Bt,
            int M, int N, int K,
            const float* __restrict__ dinv, const float* __restrict__ feat,
            void* __restrict__ Cp) {
  __shared__ __align__(16) short As[2][128 * 64];
  __shared__ __align__(16) short Bs[2][128 * 64];
  const int tid = threadIdx.x;
  const int lane = tid & 63;
  const int w = tid >> 6;
  const int wm = w >> 1, wn = w & 1;
  const int m0 = blockIdx.y * 128;
  const int n0 = blockIdx.x * 128;
  const int nt = K >> 6;

  f32x4 acc[4][4];
#pragma unroll
  for (int m = 0; m < 4; ++m)
#pragma unroll
    for (int n = 0; n < 4; ++n) acc[m][n] = (f32x4){0.f, 0.f, 0.f, 0.f};

  float4 av0[4], av1[4];

  auto stage_b = [&](int buf, int t) {
    const int kofs = t << 6;
#pragma unroll
    for (int q = 0; q < 4; ++q) {
      const int rblk = (w << 5) + (q << 3);           // wave-uniform
      const int r = rblk + (lane >> 3);
      const int sc = (lane & 7) ^ (r & 7);            // pre-swizzled source
      gld_lds16(Bt + (size_t)(n0 + r) * K + kofs + (sc << 3), &Bs[buf][rblk << 6]);
    }
  };
  auto stage_a_bf16 = [&](int buf, int t) {
    const int kofs = t << 6;
    const short* Ab = (const short*)Ap;
#pragma unroll
    for (int q = 0; q < 4; ++q) {
      const int rblk = (w << 5) + (q << 3);
      const int r = rblk + (lane >> 3);
      const int sc = (lane & 7) ^ (r & 7);
      gld_lds16(Ab + (size_t)(m0 + r) * K + kofs + (sc << 3), &As[buf][rblk << 6]);
    }
  };
  auto issue_a_f32 = [&](int t) {                     // issue-early (T14)
    const int kofs = t << 6;
    const float* Af = (const float*)Ap;
#pragma unroll
    for (int p = 0; p < 4; ++p) {
      const int r = (p << 5) + (tid >> 3);
      const int c = (tid & 7) << 3;                   // 8 contiguous elems/thread
      const float* s = Af + (size_t)(m0 + r) * K + kofs + c;
      av0[p] = *(const float4*)s;
      av1[p] = *(const float4*)(s + 4);
    }
  };
  auto write_a_f32 = [&](int buf) {                   // write-late, after compute
#pragma unroll
    for (int p = 0; p < 4; ++p) {
      const int r = (p << 5) + (tid >> 3);
      const int sc = (tid & 7) ^ (r & 7);
      *(bf16x8*)&As[buf][(r << 6) + (sc << 3)] = cvt8(av0[p], av1[p]);
    }
  };
  auto compute = [&](int buf) {
    const int lr = lane & 15, kg = lane >> 4;
#pragma unroll
    for (int kk = 0; kk < 2; ++kk) {
      const int lc = (kk << 2) + kg;
      bf16x8 a[4], b[4];
#pragma unroll
      for (int m = 0; m < 4; ++m) {
        const int r = (wm << 6) + (m << 4) + lr;
        a[m] = *(const bf16x8*)&As[buf][(r << 6) + ((lc ^ (r & 7)) << 3)];
      }
#pragma unroll
      for (int n = 0; n < 4; ++n) {
        const int r = (wn << 6) + (n << 4) + lr;
        b[n] = *(const bf16x8*)&Bs[buf][(r << 6) + ((lc ^ (r & 7)) << 3)];
      }
#pragma unroll
      for (int m = 0; m < 4; ++m)
#pragma unroll
        for (int n = 0; n < 4; ++n)
          acc[m][n] = __builtin_amdgcn_mfma_f32_16x16x32_bf16(a[m], b[n], acc[m][n], 0, 0, 0);
    }
  };

  // prologue: stage tile 0 into buf 0
  if constexpr (A_F32) { issue_a_f32(0); write_a_f32(0); } else { stage_a_bf16(0, 0); }
  stage_b(0, 0);
  __syncthreads();

  for (int t = 0; t < nt; ++t) {
    const int cur = t & 1;
    const bool more = (t + 1 < nt);
    if (more) {
      if constexpr (A_F32) issue_a_f32(t + 1); else stage_a_bf16(cur ^ 1, t + 1);
      stage_b(cur ^ 1, t + 1);
    }
    compute(cur);
    if constexpr (A_F32) { if (more) write_a_f32(cur ^ 1); }
    __syncthreads();   // compiler drains vmcnt (gld_lds) + lgkm (ds_write) here
  }

  // epilogue: C/D layout col=lane&15, row=(lane>>4)*4+j  [m89-verified]
  const int cl = lane & 15, rg = lane >> 4;
#pragma unroll
  for (int m = 0; m < 4; ++m) {
#pragma unroll
    for (int n = 0; n < 4; ++n) {
#pragma unroll
      for (int j = 0; j < 4; ++j) {
        const int gi = m0 + (wm << 6) + (m << 4) + (rg << 2) + j;
        const int gn = n0 + (wn << 6) + (n << 4) + cl;
        const float v = acc[m][n][j];
        if constexpr (GCN_EPI) {
          const float d = dinv[gi];
          const float hv = d * v + d * d * feat[(size_t)gi * NF + gn];
          ((unsigned short*)Cp)[(size_t)gi * N + gn] = f2bf_bits(hv);
        } else {
          ((float*)Cp)[(size_t)gi * N + gn] = v;
        }
      }
    }
  }
}

extern "C" void kernel_launch(void* const* d_in, const int* in_sizes, int n_in,
                              void* d_out, int out_size, void* d_ws, size_t ws_size,
                              hipStream_t stream) {
  const float* adj  = (const float*)d_in[0];
  const float* feat = (const float*)d_in[1];
  const float* W    = (const float*)d_in[2];

  // ws layout: dinv 32KB | FbT (F'^T bf16, 512x8192) 8MB | WbT (W^T bf16) 512KB | Hb bf16 8MB
  char* ws = (char*)d_ws;
  float* dinv = (float*)ws;
  short* FbT  = (short*)(ws + 32768);
  short* WbT  = (short*)(ws + 32768 + 8388608);
  short* Hb   = (short*)(ws + 32768 + 8388608 + 524288);
  float* out  = (float*)d_out;

  k_rowsum<<<NN, 256, 0, stream>>>(adj, dinv);
  k_transpose<true ><<<dim3(NF / 32, NN / 32), 256, 0, stream>>>(feat, NN, NF, dinv, FbT);
  k_transpose<false><<<dim3(NF / 32, NF / 32), 256, 0, stream>>>(W, NF, NF, nullptr, WbT);
  // H' = adj @ F' ; epilogue h = d_i*(acc) + d_i^2*feat -> Hb (bf16)
  k_gemm<true, true ><<<dim3(NF / 128, NN / 128), 256, 0, stream>>>(
      adj, FbT, NN, NF, NN, dinv, feat, Hb);
  // out = Hb @ W  (B = WbT rows are W columns)
  k_gemm<false, false><<<dim3(NF / 128, NN / 128), 256, 0, stream>>>(
      Hb, WbT, NN, NF, NF, nullptr, nullptr, out);
}

// Round 2
// 207.633 us; speedup vs baseline: 1.4409x; 1.4409x over previous
//
#include <hip/hip_runtime.h>
#include <cstdint>
#include <cstddef>

#define NN 8192
#define NF 512

typedef __attribute__((ext_vector_type(8))) short bf16x8;
typedef __attribute__((ext_vector_type(4))) float f32x4;

__device__ __forceinline__ unsigned short f2bf_bits(float f) {
  unsigned u = __builtin_bit_cast(unsigned, f);
  u += 0x7FFFu + ((u >> 16) & 1u);   // round-to-nearest-even
  return (unsigned short)(u >> 16);
}

__device__ __forceinline__ bf16x8 cvt8(float4 a, float4 b) {
  bf16x8 r;
  r[0] = (short)f2bf_bits(a.x); r[1] = (short)f2bf_bits(a.y);
  r[2] = (short)f2bf_bits(a.z); r[3] = (short)f2bf_bits(a.w);
  r[4] = (short)f2bf_bits(b.x); r[5] = (short)f2bf_bits(b.y);
  r[6] = (short)f2bf_bits(b.z); r[7] = (short)f2bf_bits(b.w);
  return r;
}

__device__ __forceinline__ void gld_lds16(const void* g, void* l) {
  __builtin_amdgcn_global_load_lds(
      (const __attribute__((address_space(1))) unsigned int*)g,
      (__attribute__((address_space(3))) unsigned int*)l, 16, 0, 0);
}

// K0: deg[i] = 1 + sum_j adj[i][j]; dinv = rsqrt(deg). CVT: also write adj as bf16.
template <bool CVT>
__global__ void k_rowsum(const float* __restrict__ adj, float* __restrict__ dinv,
                         short* __restrict__ adjb) {
  const int row = blockIdx.x;
  const float4* p = (const float4*)(adj + (size_t)row * NN);
  short* ob = CVT ? (adjb + (size_t)row * NN) : nullptr;
  float s = 0.f;
#pragma unroll
  for (int j = 0; j < 8; ++j) {
    float4 v = p[j * 256 + threadIdx.x];
    s += (v.x + v.y) + (v.z + v.w);
    if (CVT) {
      ushort4 o;
      o.x = f2bf_bits(v.x); o.y = f2bf_bits(v.y);
      o.z = f2bf_bits(v.z); o.w = f2bf_bits(v.w);
      *(ushort4*)&ob[(size_t)(j * 256 + threadIdx.x) * 4] = o;
    }
  }
#pragma unroll
  for (int off = 32; off > 0; off >>= 1) s += __shfl_down(s, off, 64);
  __shared__ float red[4];
  if ((threadIdx.x & 63) == 0) red[threadIdx.x >> 6] = s;
  __syncthreads();
  if (threadIdx.x == 0) {
    float deg = red[0] + red[1] + red[2] + red[3] + 1.0f;
    dinv[row] = (deg > 0.f) ? (1.0f / sqrtf(deg)) : 0.f;
  }
}

// K2: transpose fp32 [rows][cols] -> bf16 [cols][rows]; optional row-scale by dinv[row]
template <bool SCALE>
__global__ void k_transpose(const float* __restrict__ src, int rows, int cols,
                            const float* __restrict__ dinv, short* __restrict__ dst) {
  __shared__ float tile[32][33];
  const int c0 = blockIdx.x * 32, r0 = blockIdx.y * 32;
  const int tx = threadIdx.x & 31, ty = threadIdx.x >> 5;
#pragma unroll
  for (int i = 0; i < 32; i += 8) {
    float v = src[(size_t)(r0 + ty + i) * cols + c0 + tx];
    if (SCALE) v *= dinv[r0 + ty + i];
    tile[ty + i][tx] = v;
  }
  __syncthreads();
#pragma unroll
  for (int i = 0; i < 32; i += 8)
    dst[(size_t)(c0 + ty + i) * rows + r0 + tx] = (short)f2bf_bits(tile[tx][ty + i]);
}

// Pipelined GEMM: C[M][N] = A[M][K] * Bt[N][K]^T.
// 128x128 tile, BK=64, 512 threads = 8 waves. Waves w and w+4 share a 64x64
// out-tile; w<4 computes K-half 0 of each step, w>=4 half 1 (pair-reduced at end).
// 4-deep LDS ring (128 KB), depth-2 prefetch, ONE raw s_barrier per K-step with
// counted vmcnt (never 0 in steady state). XOR chunk-swizzle c^=(r&7), staged via
// pre-swizzled global source + linear gld_lds dest (both-sides rule).
// A_BF16: A staged via global_load_lds. Else: fp32 reg-stage+cvt, __syncthreads loop.
// GCN_EPI: out = d_i*acc + d_i^2*feat[i][n] as bf16; else fp32 store.
template <bool A_BF16, bool GCN_EPI>
__global__ __launch_bounds__(512, 2)
void k_gemm2(const void* __restrict__ Ap, const short* __restrict__ Bt,
             int N, int K,
             const float* __restrict__ dinv, const float* __restrict__ feat,
             void* __restrict__ Cp) {
  __shared__ __align__(16) short As[4][128 * 64];
  __shared__ __align__(16) short Bs[4][128 * 64];
  const int tid = threadIdx.x;
  const int lane = tid & 63;
  const int w = tid >> 6;                 // 0..7
  const int wm = (w >> 1) & 1, wn = w & 1, kk = w >> 2;

  // XCD-aware swizzle over flattened grid (bijective when nb % 8 == 0)
  const int bid = blockIdx.y * gridDim.x + blockIdx.x;
  const int nb = gridDim.x * gridDim.y;
  const int sbid = ((nb & 7) == 0) ? ((bid & 7) * (nb >> 3) + (bid >> 3)) : bid;
  const int n0 = (sbid % gridDim.x) * 128;
  const int m0 = (sbid / gridDim.x) * 128;
  const int nt = K >> 6;

  f32x4 acc[4][4];
#pragma unroll
  for (int m = 0; m < 4; ++m)
#pragma unroll
    for (int n = 0; n < 4; ++n) acc[m][n] = (f32x4){0.f, 0.f, 0.f, 0.f};

  auto stage_b = [&](int buf, int t) {
    const int kofs = t << 6;
#pragma unroll
    for (int q = 0; q < 2; ++q) {
      const int rblk = (w << 4) + (q << 3);          // wave-uniform LDS base
      const int r = rblk + (lane >> 3);
      const int sc = (lane & 7) ^ (r & 7);           // pre-swizzled source chunk
      gld_lds16(Bt + (size_t)(n0 + r) * K + kofs + (sc << 3), &Bs[buf][rblk << 6]);
    }
  };
  auto stage_a = [&](int buf, int t) {
    const int kofs = t << 6;
    if constexpr (A_BF16) {
      const short* Ab = (const short*)Ap;
#pragma unroll
      for (int q = 0; q < 2; ++q) {
        const int rblk = (w << 4) + (q << 3);
        const int r = rblk + (lane >> 3);
        const int sc = (lane & 7) ^ (r & 7);
        gld_lds16(Ab + (size_t)(m0 + r) * K + kofs + (sc << 3), &As[buf][rblk << 6]);
      }
    } else {
      const float* Af = (const float*)Ap;
      const int r = tid >> 2;
      const int c0 = (tid & 3) << 4;                 // 16 fp32 per thread
      const float* s = Af + (size_t)(m0 + r) * K + kofs + c0;
      float4 x0 = ((const float4*)s)[0], x1 = ((const float4*)s)[1];
      float4 x2 = ((const float4*)s)[2], x3 = ((const float4*)s)[3];
      const int cc = (tid & 3) << 1;                 // logical chunk pair
      *(bf16x8*)&As[buf][(r << 6) + ((cc ^ (r & 7)) << 3)]       = cvt8(x0, x1);
      *(bf16x8*)&As[buf][(r << 6) + (((cc + 1) ^ (r & 7)) << 3)] = cvt8(x2, x3);
    }
  };
  auto compute = [&](int buf) {
    const int lr = lane & 15, kg = lane >> 4;
    const int lc = (kk << 2) + kg;                   // this wave's K-chunk
    bf16x8 a[4], b[4];
#pragma unroll
    for (int m = 0; m < 4; ++m) {
      const int r = (wm << 6) + (m << 4) + lr;
      a[m] = *(const bf16x8*)&As[buf][(r << 6) + ((lc ^ (r & 7)) << 3)];
    }
#pragma unroll
    for (int n = 0; n < 4; ++n) {
      const int r = (wn << 6) + (n << 4) + lr;
      b[n] = *(const bf16x8*)&Bs[buf][(r << 6) + ((lc ^ (r & 7)) << 3)];
    }
    __builtin_amdgcn_s_setprio(1);
#pragma unroll
    for (int m = 0; m < 4; ++m)
#pragma unroll
      for (int n = 0; n < 4; ++n)
        acc[m][n] = __builtin_amdgcn_mfma_f32_16x16x32_bf16(a[m], b[n], acc[m][n], 0, 0, 0);
    __builtin_amdgcn_s_setprio(0);
  };

  // prologue: prefetch tiles 0 and 1
  stage_a(0, 0); stage_b(0, 0);
  stage_a(1, 1); stage_b(1, 1);

  for (int t = 0; t < nt; ++t) {
    if (t + 2 < nt) { stage_a((t + 2) & 3, t + 2); stage_b((t + 2) & 3, t + 2); }
    if constexpr (A_BF16) {
      // counted vmcnt: 4 gld_lds per wave per tile, 2 tiles in flight
      if (t + 2 < nt)      asm volatile("s_waitcnt vmcnt(8)" ::: "memory");
      else if (t + 1 < nt) asm volatile("s_waitcnt vmcnt(4)" ::: "memory");
      else                 asm volatile("s_waitcnt vmcnt(0)" ::: "memory");
      __builtin_amdgcn_s_barrier();
      __builtin_amdgcn_sched_barrier(0);             // keep ds_reads below the wait
    } else {
      __syncthreads();                               // full drain (covers ds_writes)
    }
    compute(t & 3);
  }

  // pair reduction: waves 4-7 dump acc, waves 0-3 add. Reuse As (64 KB).
  __syncthreads();
  float* red = (float*)&As[0][0];
  if (w >= 4) {
    float* my = red + ((w - 4) << 12);
#pragma unroll
    for (int m = 0; m < 4; ++m)
#pragma unroll
      for (int n = 0; n < 4; ++n)
        *(f32x4*)&my[(((m << 2) + n) << 8) + (lane << 2)] = acc[m][n];
  }
  __syncthreads();
  if (w < 4) {
    float* my = red + (w << 12);
#pragma unroll
    for (int m = 0; m < 4; ++m)
#pragma unroll
      for (int n = 0; n < 4; ++n)
        acc[m][n] += *(const f32x4*)&my[(((m << 2) + n) << 8) + (lane << 2)];

    const int cl = lane & 15, rg = lane >> 4;
#pragma unroll
    for (int m = 0; m < 4; ++m) {
#pragma unroll
      for (int n = 0; n < 4; ++n) {
#pragma unroll
        for (int j = 0; j < 4; ++j) {
          const int gi = m0 + (wm << 6) + (m << 4) + (rg << 2) + j;
          const int gn = n0 + (wn << 6) + (n << 4) + cl;
          const float v = acc[m][n][j];
          if constexpr (GCN_EPI) {
            const float d = dinv[gi];
            const float hv = d * v + d * d * feat[(size_t)gi * NF + gn];
            ((unsigned short*)Cp)[(size_t)gi * N + gn] = f2bf_bits(hv);
          } else {
            ((float*)Cp)[(size_t)gi * N + gn] = v;
          }
        }
      }
    }
  }
}

extern "C" void kernel_launch(void* const* d_in, const int* in_sizes, int n_in,
                              void* d_out, int out_size, void* d_ws, size_t ws_size,
                              hipStream_t stream) {
  const float* adj  = (const float*)d_in[0];
  const float* feat = (const float*)d_in[1];
  const float* W    = (const float*)d_in[2];

  // ws: dinv 32KB | FbT 8MB | WbT 512KB | Hb 8MB | adjb 128MB (optional)
  char* ws = (char*)d_ws;
  float* dinv = (float*)ws;
  short* FbT  = (short*)(ws + 32768);
  short* WbT  = (short*)(ws + 32768 + 8388608);
  short* Hb   = (short*)(ws + 32768 + 8388608 + 524288);
  short* adjb = (short*)(ws + 32768 + 8388608 + 524288 + 8388608);
  float* out  = (float*)d_out;
  const bool big_ws = ws_size >= (size_t)(32768 + 8388608 + 524288 + 8388608) +
                                 (size_t)NN * NN * 2;

  if (big_ws) {
    k_rowsum<true><<<NN, 256, 0, stream>>>(adj, dinv, adjb);
  } else {
    k_rowsum<false><<<NN, 256, 0, stream>>>(adj, dinv, nullptr);
  }
  k_transpose<true ><<<dim3(NF / 32, NN / 32), 256, 0, stream>>>(feat, NN, NF, dinv, FbT);
  k_transpose<false><<<dim3(NF / 32, NF / 32), 256, 0, stream>>>(W, NF, NF, nullptr, WbT);

  if (big_ws) {
    k_gemm2<true, true ><<<dim3(NF / 128, NN / 128), 512, 0, stream>>>(
        adjb, FbT, NF, NN, dinv, feat, Hb);
  } else {
    k_gemm2<false, true ><<<dim3(NF / 128, NN / 128), 512, 0, stream>>>(
        adj, FbT, NF, NN, dinv, feat, Hb);
  }
  k_gemm2<true, false><<<dim3(NF / 128, NN / 128), 512, 0, stream>>>(
      Hb, WbT, NF, NF, nullptr, nullptr, out);
}

// Round 3
// 205.058 us; speedup vs baseline: 1.4590x; 1.0126x over previous
//
#include <hip/hip_runtime.h>
#include <cstdint>
#include <cstddef>

#define NN 8192
#define NF 512

typedef __attribute__((ext_vector_type(8))) short bf16x8;
typedef __attribute__((ext_vector_type(4))) float f32x4;

__device__ __forceinline__ unsigned short f2bf_bits(float f) {
  unsigned u = __builtin_bit_cast(unsigned, f);
  u += 0x7FFFu + ((u >> 16) & 1u);   // round-to-nearest-even
  return (unsigned short)(u >> 16);
}

__device__ __forceinline__ bf16x8 cvt8(float4 a, float4 b) {
  bf16x8 r;
  r[0] = (short)f2bf_bits(a.x); r[1] = (short)f2bf_bits(a.y);
  r[2] = (short)f2bf_bits(a.z); r[3] = (short)f2bf_bits(a.w);
  r[4] = (short)f2bf_bits(b.x); r[5] = (short)f2bf_bits(b.y);
  r[6] = (short)f2bf_bits(b.z); r[7] = (short)f2bf_bits(b.w);
  return r;
}

__device__ __forceinline__ void gld_lds16(const void* g, void* l) {
  __builtin_amdgcn_global_load_lds(
      (const __attribute__((address_space(1))) unsigned int*)g,
      (__attribute__((address_space(3))) unsigned int*)l, 16, 0, 0);
}

// K0: deg[i] = 1 + sum_j adj[i][j]; dinv = rsqrt(deg). CVT: also write adj as bf16.
template <bool CVT>
__global__ void k_rowsum(const float* __restrict__ adj, float* __restrict__ dinv,
                         short* __restrict__ adjb) {
  const int row = blockIdx.x;
  const float4* p = (const float4*)(adj + (size_t)row * NN);
  short* ob = CVT ? (adjb + (size_t)row * NN) : nullptr;
  float s = 0.f;
#pragma unroll
  for (int j = 0; j < 8; ++j) {
    float4 v = p[j * 256 + threadIdx.x];
    s += (v.x + v.y) + (v.z + v.w);
    if (CVT) {
      ushort4 o;
      o.x = f2bf_bits(v.x); o.y = f2bf_bits(v.y);
      o.z = f2bf_bits(v.z); o.w = f2bf_bits(v.w);
      *(ushort4*)&ob[(size_t)(j * 256 + threadIdx.x) * 4] = o;
    }
  }
#pragma unroll
  for (int off = 32; off > 0; off >>= 1) s += __shfl_down(s, off, 64);
  __shared__ float red[4];
  if ((threadIdx.x & 63) == 0) red[threadIdx.x >> 6] = s;
  __syncthreads();
  if (threadIdx.x == 0) {
    float deg = red[0] + red[1] + red[2] + red[3] + 1.0f;
    dinv[row] = (deg > 0.f) ? (1.0f / sqrtf(deg)) : 0.f;
  }
}

// K2: transpose fp32 [rows][cols] -> bf16 [cols][rows]; optional row-scale by dinv[row]
template <bool SCALE>
__global__ void k_transpose(const float* __restrict__ src, int rows, int cols,
                            const float* __restrict__ dinv, short* __restrict__ dst) {
  __shared__ float tile[32][33];
  const int c0 = blockIdx.x * 32, r0 = blockIdx.y * 32;
  const int tx = threadIdx.x & 31, ty = threadIdx.x >> 5;
#pragma unroll
  for (int i = 0; i < 32; i += 8) {
    float v = src[(size_t)(r0 + ty + i) * cols + c0 + tx];
    if (SCALE) v *= dinv[r0 + ty + i];
    tile[ty + i][tx] = v;
  }
  __syncthreads();
#pragma unroll
  for (int i = 0; i < 32; i += 8)
    dst[(size_t)(c0 + ty + i) * rows + r0 + tx] = (short)f2bf_bits(tile[tx][ty + i]);
}

// Pipelined GEMM: C[M][N] = A[M][K] * Bt[N][K]^T.
// 128x128 tile, BK=64, 512 threads = 8 waves (2x2 x K-split-2).
// Ring-4 LDS (128 KB), depth-2 prefetch. Two fine-interleaved phases per K-step:
//   P0: {ds_read a[4],b[0..1] || issue stage_A(t+2); barrier; lgkm0; prio1; 8 MFMA}
//   P1: {ds_read b[2..3]      || issue stage_B(t+2); lgkm0; prio1; 8 MFMA;
//        vmcnt(4) [counted, never 0 steady-state]; barrier}
// XOR chunk-swizzle c^=(r&7) staged via pre-swizzled global source (both-sides rule).
template <bool A_BF16, bool GCN_EPI>
__global__ __launch_bounds__(512, 2)
void k_gemm2(const void* __restrict__ Ap, const short* __restrict__ Bt,
             int N, int K,
             const float* __restrict__ dinv, const float* __restrict__ feat,
             void* __restrict__ Cp) {
  __shared__ __align__(16) short As[4][128 * 64];
  __shared__ __align__(16) short Bs[4][128 * 64];
  const int tid = threadIdx.x;
  const int lane = tid & 63;
  const int w = tid >> 6;                 // 0..7
  const int wm = (w >> 1) & 1, wn = w & 1, kk = w >> 2;

  const int bid = blockIdx.y * gridDim.x + blockIdx.x;
  const int nb = gridDim.x * gridDim.y;
  const int sbid = ((nb & 7) == 0) ? ((bid & 7) * (nb >> 3) + (bid >> 3)) : bid;
  const int n0 = (sbid % gridDim.x) * 128;
  const int m0 = (sbid / gridDim.x) * 128;
  const int nt = K >> 6;

  f32x4 acc[4][4];
#pragma unroll
  for (int m = 0; m < 4; ++m)
#pragma unroll
    for (int n = 0; n < 4; ++n) acc[m][n] = (f32x4){0.f, 0.f, 0.f, 0.f};

  const int lr = lane & 15, kg = lane >> 4;
  const int lc = (kk << 2) + kg;                   // this wave's K-chunk (of 8)

  auto stage_b = [&](int buf, int t) {
    const int kofs = t << 6;
#pragma unroll
    for (int q = 0; q < 2; ++q) {
      const int rblk = (w << 4) + (q << 3);        // wave-uniform LDS base
      const int r = rblk + (lane >> 3);
      const int sc = (lane & 7) ^ (r & 7);         // pre-swizzled source chunk
      gld_lds16(Bt + (size_t)(n0 + r) * K + kofs + (sc << 3), &Bs[buf][rblk << 6]);
    }
  };
  auto stage_a = [&](int buf, int t) {
    const int kofs = t << 6;
    const short* Ab = (const short*)Ap;
#pragma unroll
    for (int q = 0; q < 2; ++q) {
      const int rblk = (w << 4) + (q << 3);
      const int r = rblk + (lane >> 3);
      const int sc = (lane & 7) ^ (r & 7);
      gld_lds16(Ab + (size_t)(m0 + r) * K + kofs + (sc << 3), &As[buf][rblk << 6]);
    }
  };
  auto stage_a_f32 = [&](int buf, int t) {         // fallback path (no adjb ws)
    const int kofs = t << 6;
    const float* Af = (const float*)Ap;
    const int r = tid >> 2;
    const int c0 = (tid & 3) << 4;
    const float* s = Af + (size_t)(m0 + r) * K + kofs + c0;
    float4 x0 = ((const float4*)s)[0], x1 = ((const float4*)s)[1];
    float4 x2 = ((const float4*)s)[2], x3 = ((const float4*)s)[3];
    const int cc = (tid & 3) << 1;
    *(bf16x8*)&As[buf][(r << 6) + ((cc ^ (r & 7)) << 3)]       = cvt8(x0, x1);
    *(bf16x8*)&As[buf][(r << 6) + (((cc + 1) ^ (r & 7)) << 3)] = cvt8(x2, x3);
  };

  auto read_a = [&](int buf, bf16x8* a) {
#pragma unroll
    for (int m = 0; m < 4; ++m) {
      const int r = (wm << 6) + (m << 4) + lr;
      a[m] = *(const bf16x8*)&As[buf][(r << 6) + ((lc ^ (r & 7)) << 3)];
    }
  };
  auto read_b2 = [&](int buf, int nh, bf16x8* b) {
#pragma unroll
    for (int i = 0; i < 2; ++i) {
      const int r = (wn << 6) + (((nh << 1) + i) << 4) + lr;
      b[i] = *(const bf16x8*)&Bs[buf][(r << 6) + ((lc ^ (r & 7)) << 3)];
    }
  };
  auto mfma8 = [&](bf16x8* a, bf16x8* b, int nh) {
#pragma unroll
    for (int m = 0; m < 4; ++m)
#pragma unroll
      for (int i = 0; i < 2; ++i)
        acc[m][(nh << 1) + i] =
            __builtin_amdgcn_mfma_f32_16x16x32_bf16(a[m], b[i], acc[m][(nh << 1) + i], 0, 0, 0);
  };

  if constexpr (A_BF16) {
    // prologue: prefetch tiles 0 and 1 (4 gld_lds per wave per tile)
    stage_a(0, 0); stage_b(0, 0);
    stage_a(1, 1); stage_b(1, 1);
    asm volatile("s_waitcnt vmcnt(4)" ::: "memory");   // tile 0 resident
    __builtin_amdgcn_s_barrier();
    __builtin_amdgcn_sched_barrier(0);

    for (int t = 0; t < nt; ++t) {
      const int cur = t & 3;
      const bool more = (t + 2 < nt);
      bf16x8 a[4], b0[2], b1[2];
      // ---- phase 0 ----
      read_a(cur, a);
      read_b2(cur, 0, b0);
      if (more) stage_a((t + 2) & 3, t + 2);
      __builtin_amdgcn_s_barrier();
      asm volatile("s_waitcnt lgkmcnt(0)" ::: "memory");
      __builtin_amdgcn_sched_barrier(0);
      __builtin_amdgcn_s_setprio(1);
      mfma8(a, b0, 0);
      __builtin_amdgcn_s_setprio(0);
      __builtin_amdgcn_sched_barrier(0);
      // ---- phase 1 ----
      read_b2(cur, 1, b1);
      if (more) stage_b((t + 2) & 3, t + 2);
      asm volatile("s_waitcnt lgkmcnt(0)" ::: "memory");
      __builtin_amdgcn_sched_barrier(0);
      __builtin_amdgcn_s_setprio(1);
      mfma8(a, b1, 1);
      __builtin_amdgcn_s_setprio(0);
      __builtin_amdgcn_sched_barrier(0);
      // ---- tile boundary: counted drain of tile t+1 ----
      if (more)                asm volatile("s_waitcnt vmcnt(4)" ::: "memory");
      else if (t + 1 < nt)     asm volatile("s_waitcnt vmcnt(0)" ::: "memory");
      __builtin_amdgcn_s_barrier();
      __builtin_amdgcn_sched_barrier(0);
    }
  } else {
    // fallback: fp32 A reg-staged+cvt, drain semantics
    stage_a_f32(0, 0); stage_b(0, 0);
    stage_a_f32(1, 1); stage_b(1, 1);
    __syncthreads();
    for (int t = 0; t < nt; ++t) {
      const int cur = t & 3;
      if (t + 2 < nt) { stage_a_f32((t + 2) & 3, t + 2); stage_b((t + 2) & 3, t + 2); }
      bf16x8 a[4], b0[2], b1[2];
      read_a(cur, a); read_b2(cur, 0, b0); read_b2(cur, 1, b1);
      __builtin_amdgcn_s_setprio(1);
      mfma8(a, b0, 0); mfma8(a, b1, 1);
      __builtin_amdgcn_s_setprio(0);
      __syncthreads();
    }
  }

  // pair reduction across kk halves: waves 4-7 dump acc, waves 0-3 add. Reuse As.
  __syncthreads();
  float* red = (float*)&As[0][0];
  if (w >= 4) {
    float* my = red + ((w - 4) << 12);
#pragma unroll
    for (int m = 0; m < 4; ++m)
#pragma unroll
      for (int n = 0; n < 4; ++n)
        *(f32x4*)&my[(((m << 2) + n) << 8) + (lane << 2)] = acc[m][n];
  }
  __syncthreads();
  if (w < 4) {
    float* my = red + (w << 12);
#pragma unroll
    for (int m = 0; m < 4; ++m)
#pragma unroll
      for (int n = 0; n < 4; ++n)
        acc[m][n] += *(const f32x4*)&my[(((m << 2) + n) << 8) + (lane << 2)];

    const int cl = lane & 15, rg = lane >> 4;
#pragma unroll
    for (int m = 0; m < 4; ++m) {
#pragma unroll
      for (int n = 0; n < 4; ++n) {
#pragma unroll
        for (int j = 0; j < 4; ++j) {
          const int gi = m0 + (wm << 6) + (m << 4) + (rg << 2) + j;
          const int gn = n0 + (wn << 6) + (n << 4) + cl;
          const float v = acc[m][n][j];
          if constexpr (GCN_EPI) {
            const float d = dinv[gi];
            const float hv = d * v + d * d * feat[(size_t)gi * NF + gn];
            ((unsigned short*)Cp)[(size_t)gi * N + gn] = f2bf_bits(hv);
          } else {
            ((float*)Cp)[(size_t)gi * N + gn] = v;
          }
        }
      }
    }
  }
}

extern "C" void kernel_launch(void* const* d_in, const int* in_sizes, int n_in,
                              void* d_out, int out_size, void* d_ws, size_t ws_size,
                              hipStream_t stream) {
  const float* adj  = (const float*)d_in[0];
  const float* feat = (const float*)d_in[1];
  const float* W    = (const float*)d_in[2];

  // ws: dinv 32KB | FbT 8MB | WbT 512KB | Hb 8MB | adjb 128MB (optional)
  char* ws = (char*)d_ws;
  float* dinv = (float*)ws;
  short* FbT  = (short*)(ws + 32768);
  short* WbT  = (short*)(ws + 32768 + 8388608);
  short* Hb   = (short*)(ws + 32768 + 8388608 + 524288);
  short* adjb = (short*)(ws + 32768 + 8388608 + 524288 + 8388608);
  float* out  = (float*)d_out;
  const bool big_ws = ws_size >= (size_t)(32768 + 8388608 + 524288 + 8388608) +
                                 (size_t)NN * NN * 2;

  if (big_ws) {
    k_rowsum<true><<<NN, 256, 0, stream>>>(adj, dinv, adjb);
  } else {
    k_rowsum<false><<<NN, 256, 0, stream>>>(adj, dinv, nullptr);
  }
  k_transpose<true ><<<dim3(NF / 32, NN / 32), 256, 0, stream>>>(feat, NN, NF, dinv, FbT);
  k_transpose<false><<<dim3(NF / 32, NF / 32), 256, 0, stream>>>(W, NF, NF, nullptr, WbT);

  if (big_ws) {
    k_gemm2<true, true ><<<dim3(NF / 128, NN / 128), 512, 0, stream>>>(
        adjb, FbT, NF, NN, dinv, feat, Hb);
  } else {
    k_gemm2<false, true ><<<dim3(NF / 128, NN / 128), 512, 0, stream>>>(
        adj, FbT, NF, NN, dinv, feat, Hb);
  }
  k_gemm2<true, false><<<dim3(NF / 128, NN / 128), 512, 0, stream>>>(
      Hb, WbT, NF, NF, nullptr, nullptr, out);
}